// Round 8
// baseline (2417.570 us; speedup 1.0000x reference)
//
#include <hip/hip_runtime.h>
#include <cstdint>

#define NB 512   // batch
#define ND 128   // D
#define NW 256   // timesteps
#define NH 256   // hidden
#define PGRP 32  // row groups (M=16 rows each)
#define QGRP 8   // col groups (32 h-cols each)
#define SENT32 0x7C007C00u
#define SENT64 0x7C007C007C007C00ull

typedef _Float16 f16;
typedef _Float16 h8 __attribute__((ext_vector_type(8)));
typedef float f32x4 __attribute__((ext_vector_type(4)));
typedef unsigned long long u64;

__device__ __forceinline__ float sigm(float v){ return 1.f/(1.f+__expf(-v)); }
__device__ __forceinline__ float tanh_fast(float v){
  v = fminf(fmaxf(v,-15.f),15.f);
  float e = __expf(2.f*v);
  return (e-1.f)/(e+1.f);
}

// ---------------------------------------------------------------------------
// a[b,d] = softmax_d( x[b,d,:] . w_x + attn_b )   (h/c term cancels in softmax)
// ---------------------------------------------------------------------------
__global__ __launch_bounds__(128) void attn_kernel(
    const float* __restrict__ x, const float* __restrict__ attn_w,
    const float* __restrict__ attn_b, float* __restrict__ a_buf)
{
    __shared__ float wx[NW];
    __shared__ float sred[2];
    const int b = blockIdx.x;
    const int d = threadIdx.x;

    wx[d]       = attn_w[2 * NH + d];
    wx[d + 128] = attn_w[2 * NH + d + 128];
    __syncthreads();

    const float4* xr = (const float4*)(x + ((size_t)b * ND + d) * NW);
    float acc = 0.f;
    #pragma unroll 8
    for (int w4 = 0; w4 < NW / 4; ++w4) {
        float4 v = xr[w4];
        acc += v.x * wx[w4*4+0] + v.y * wx[w4*4+1]
             + v.z * wx[w4*4+2] + v.w * wx[w4*4+3];
    }
    float e = acc + attn_b[0];

    float mx = e;
    #pragma unroll
    for (int o = 32; o > 0; o >>= 1) mx = fmaxf(mx, __shfl_xor(mx, o));
    if ((d & 63) == 0) sred[d >> 6] = mx;
    __syncthreads();
    mx = fmaxf(sred[0], sred[1]);
    __syncthreads();

    float p = __expf(e - mx);
    float s = p;
    #pragma unroll
    for (int o = 32; o > 0; o >>= 1) s += __shfl_xor(s, o);
    if ((d & 63) == 0) sred[d >> 6] = s;
    __syncthreads();
    s = sred[0] + sred[1];

    a_buf[(size_t)b * ND + d] = p / s;
}

// ---------------------------------------------------------------------------
// Pack W_aug = [W_hh | W_ih] into per-(q,wave,ktile) MFMA B-fragments (fp16).
// B-frag (16x16x32): lane l holds B[k = kt*32 + (l>>4)*8 + e][col16 = l&15],
// col16 -> (hcol_local = col16>>2, gate = col16&3).  (identical to round 3)
// ---------------------------------------------------------------------------
__global__ __launch_bounds__(512) void pack_kernel(
    const float* __restrict__ W_ih, const float* __restrict__ W_hh,
    const float* __restrict__ b_ih, const float* __restrict__ b_hh,
    f16* __restrict__ Wfrag, float* __restrict__ bias)
{
    int flat = blockIdx.x * 512 + threadIdx.x;   // 0..49151
    int l    = flat & 63;
    int kt   = (flat >> 6) % 12;
    int wq   = (flat >> 6) / 12;                 // q*8 + w
    int col16 = l & 15, kb = l >> 4;
    int hcol = (wq >> 3) * 32 + (wq & 7) * 4 + (col16 >> 2);
    int gate = col16 & 3;
    int n    = gate * 256 + hcol;
    int k0   = kt * 32 + kb * 8;

    f16 tmp[8];
    #pragma unroll
    for (int e = 0; e < 8; ++e) {
        int k = k0 + e;
        float v = (k < NH) ? W_hh[(size_t)n * NH + k]
                           : W_ih[(size_t)n * ND + (k - NH)];
        tmp[e] = (f16)v;
    }
    *(h8*)(Wfrag + (size_t)flat * 8) = *(const h8*)tmp;

    if (flat < 1024) bias[flat] = b_ih[flat] + b_hh[flat];
}

// poison all 8 hx slots with fp16-inf sentinel (|h|<1 always)
__global__ __launch_bounds__(512) void poison_kernel(uint4* __restrict__ hx4)
{
    uint4 v = {SENT32, SENT32, SENT32, SENT32};
    hx4[(size_t)blockIdx.x * 512 + threadIdx.x] = v;   // 256 blocks -> 2 MB
}

// ---------------------------------------------------------------------------
// Persistent LSTM: 256 blocks (bid = q*32 + p), 512 threads (8 waves).
// Block (p,q): rows p*16..+16, h-cols q*32..+32 (wave w: 16 gate-cols).
// Per step t:
//  (a) pollers (tid<128, chunk pc!=q) ISSUE 8 u64 probes of slot (t-1)
//  (b) x-part MFMA (kt 8..11) from buf[t&1]           [probe latency hidden]
//  (c) pollers: detect (self-flagging, fp16-inf sentinel), land 64B into LDS,
//      then poison own assigned chunk (pc==(q+1)&7) of slot (t-2)&7
//  B1  (d) h-part MFMA kt 0..7   [own chunk q was written locally at (e,t-1)]
//  (e) quad-shfl gate transpose -> LSTM cell -> publish (8B agent stores)
//      + own-h -> LDS buf[(t+1)&1] + out store
//  (f) stage a*x(t+1) -> buf[(t+1)&1];  vmcnt(0) drain;  B2
// Ordering: poison@t acked at end-of-t drain, before publish h(t+1); any
// producer rewriting that slot (step t+6) first observes h(t+1). Deadlock-
// free: every block publishes step t before it can wait on step t data.
// ---------------------------------------------------------------------------
__global__ __launch_bounds__(512, 2) void lstm_kernel(
    const float* __restrict__ x, const float* __restrict__ a_buf,
    const float* __restrict__ bias, const f16* __restrict__ Wfrag,
    f16* __restrict__ hx, float* __restrict__ out)
{
    __shared__ __align__(16) unsigned char A16[2][16 * 768];  // 2 x 12 KB

    const int tid = threadIdx.x;
    const int w = tid >> 6, l = tid & 63;
    const int p = blockIdx.x & 31, q = blockIdx.x >> 5;
    const int b0 = p * 16;

    // --- weights -> registers (persistent) ---
    h8 bfrag[12];
    {
        const h8* wsrc = (const h8*)Wfrag + ((q * 8 + w) * 12) * 64 + l;
        #pragma unroll
        for (int kt = 0; kt < 12; ++kt) bfrag[kt] = wsrc[kt * 64];
    }

    // --- epilogue lane roles (post quad-transpose) ---
    const int erow = 4 * (l >> 4) + (l & 3);   // row this lane finalizes
    const int ehc  = (l & 15) >> 2;            // hcol within wave (0..3)
    const int jcol = q * 32 + w * 4 + ehc;     // global h col
    float bias4[4];
    #pragma unroll
    for (int g = 0; g < 4; ++g) bias4[g] = bias[g * 256 + jcol];
    float cstate = 0.f;

    // --- roles ---
    const int arow = l & 15, akb = l >> 4;     // A-frag read
    const int xrow = tid >> 4, xdc = tid & 15; // x loader (tid<256)
    const int prow = tid >> 3, pc = tid & 7;   // poller (tid<128)
    const bool pact = (tid < 128) && (pc != q);
    const bool poisoner = (tid < 128) && (pc == ((q + 1) & 7));

    float areg[8];
    const float* xbase = x;
    if (tid < 256) {
        int b = b0 + xrow;
        #pragma unroll
        for (int e = 0; e < 8; ++e) areg[e] = a_buf[b * ND + xdc * 8 + e];
        xbase = x + ((size_t)b * ND + xdc * 8) * NW;
    }
    float4 xq[8];

    // --- prologue: zero h-region of buf0; stage x_hat(0) ---
    {
        int byte = (tid >> 5) * 768 + (tid & 31) * 16;
        byte ^= ((tid >> 5) & 7) << 4;
        h8 z = {};
        *(h8*)(A16[0] + byte) = z;
    }
    if (tid < 256) {
        #pragma unroll
        for (int e = 0; e < 8; ++e)
            xq[e] = *(const float4*)(xbase + (size_t)e * NW);
        f16 xv[8];
        #pragma unroll
        for (int e = 0; e < 8; ++e) {
            float xf = xq[e].x;
            xq[e] = make_float4(xq[e].y, xq[e].z, xq[e].w, xq[e].x);
            xv[e] = (f16)(xf * areg[e]);
        }
        int byte = xrow * 768 + 512 + xdc * 16;
        byte ^= (xrow & 7) << 4;
        *(h8*)(A16[0] + byte) = *(const h8*)xv;
    }
    __syncthreads();

    for (int t = 0; t < NW; ++t) {
        // --- (a) issue probes for slot (t-1) ---
        u64 dv[8];
        u64* hbase = nullptr;
        if (t > 0 && pact) {
            hbase = (u64*)hx + (((size_t)((t - 1) & 7)) * NB + b0 + prow) * 64 + pc * 8;
            #pragma unroll
            for (int k = 0; k < 8; ++k)
                dv[k] = __hip_atomic_load(hbase + k,
                        __ATOMIC_RELAXED, __HIP_MEMORY_SCOPE_AGENT);
        }

        // --- (b) x-part MFMA (kt 8..11) ---
        f32x4 acc = {0.f, 0.f, 0.f, 0.f};
        #pragma unroll
        for (int kt = 8; kt < 12; ++kt) {
            int byte = arow * 768 + kt * 64 + akb * 16;
            byte ^= (arow & 7) << 4;
            h8 afrag = *(const h8*)(A16[t & 1] + byte);
            acc = __builtin_amdgcn_mfma_f32_16x16x32_f16(afrag, bfrag[kt], acc, 0, 0, 0);
        }

        // --- (c) detect + land remote h; poison slot (t-2)&7 ---
        if (t > 0 && pact) {
            for (;;) {
                bool ok = true;
                #pragma unroll
                for (int k = 0; k < 8; ++k)
                    ok = ok && ((unsigned)dv[k] != SENT32)
                            && ((unsigned)(dv[k] >> 32) != SENT32);
                if (ok) break;
                __builtin_amdgcn_s_sleep(1);
                #pragma unroll
                for (int k = 0; k < 8; ++k)
                    dv[k] = __hip_atomic_load(hbase + k,
                            __ATOMIC_RELAXED, __HIP_MEMORY_SCOPE_AGENT);
            }
            int base = prow * 768 + pc * 64;
            #pragma unroll
            for (int j = 0; j < 4; ++j) {
                int ad = (base + j * 16) ^ ((prow & 7) << 4);
                u64* pp = (u64*)(A16[t & 1] + ad);
                pp[0] = dv[2 * j];
                pp[1] = dv[2 * j + 1];
            }
            if (poisoner) {
                u64* pz = (u64*)hx + (((size_t)((t + 6) & 7)) * NB + b0 + prow) * 64 + pc * 8;
                #pragma unroll
                for (int k = 0; k < 8; ++k)
                    __hip_atomic_store(pz + k, SENT64,
                            __ATOMIC_RELAXED, __HIP_MEMORY_SCOPE_AGENT);
            }
        }
        __syncthreads();   // B1: full h(t-1) in LDS

        // --- (d) h-part MFMA (kt 0..7) ---
        #pragma unroll
        for (int kt = 0; kt < 8; ++kt) {
            int byte = arow * 768 + kt * 64 + akb * 16;
            byte ^= (arow & 7) << 4;
            h8 afrag = *(const h8*)(A16[t & 1] + byte);
            acc = __builtin_amdgcn_mfma_f32_16x16x32_f16(afrag, bfrag[kt], acc, 0, 0, 0);
        }

        // --- (e) quad transpose (4 shfl), cell, publish, feedback, out ---
        float v0 = acc[0], v1 = acc[1], v2 = acc[2], v3 = acc[3];
        {
            float t0 = __shfl_xor((l & 1) ? v0 : v1, 1);
            float t1 = __shfl_xor((l & 1) ? v2 : v3, 1);
            if (l & 1) { v0 = t0; v2 = t1; } else { v1 = t0; v3 = t1; }
            float t2 = __shfl_xor((l & 2) ? v0 : v2, 2);
            float t3 = __shfl_xor((l & 2) ? v1 : v3, 2);
            if (l & 2) { v0 = t2; v1 = t3; } else { v2 = t2; v3 = t3; }
        }
        float G0 = v0 + bias4[0], G1 = v1 + bias4[1];
        float G2 = v2 + bias4[2], G3 = v3 + bias4[3];
        float ig = sigm(G0), fg = sigm(G1);
        float gg = tanh_fast(G2), og = sigm(G3);
        cstate = fg * cstate + ig * gg;
        float hn = og * tanh_fast(cstate);

        f16 hf = (f16)hn;
        unsigned hb = (unsigned)__builtin_bit_cast(unsigned short, hf);
        unsigned ph = (unsigned)__shfl_xor((int)hb, 4);
        unsigned pair = hb | (ph << 16);
        unsigned hi = (unsigned)__shfl_xor((int)pair, 8);
        if ((l & 12) == 0) {   // one 8B store per (row, wave): cols w*4..+3
            u64 val = (u64)pair | ((u64)hi << 32);
            u64* dst = (u64*)hx + (((size_t)(t & 7)) * NB + b0 + erow) * 64 + q * 8 + w;
            __hip_atomic_store(dst, val, __ATOMIC_RELAXED, __HIP_MEMORY_SCOPE_AGENT);
        }
        // own-half feedback straight into next buffer (no L3 round trip)
        {
            int byte = erow * 768 + jcol * 2;
            byte ^= (erow & 7) << 4;
            *(f16*)(A16[(t + 1) & 1] + byte) = hf;
        }
        out[((size_t)(b0 + erow) * NW + t) * NH + jcol] = hn;

        // --- (f) stage x_hat(t+1) into buf[(t+1)&1] ---
        if (tid < 256 && t + 1 < NW) {
            if (((t + 1) & 3) == 0) {
                #pragma unroll
                for (int e = 0; e < 8; ++e)
                    xq[e] = *(const float4*)(xbase + (size_t)e * NW + (t + 1));
            }
            f16 xv[8];
            #pragma unroll
            for (int e = 0; e < 8; ++e) {
                float xf = xq[e].x;
                xq[e] = make_float4(xq[e].y, xq[e].z, xq[e].w, xq[e].x);
                xv[e] = (f16)(xf * areg[e]);
            }
            int byte = xrow * 768 + 512 + xdc * 16;
            byte ^= (xrow & 7) << 4;
            *(h8*)(A16[(t + 1) & 1] + byte) = *(const h8*)xv;
        }

        // drain this step's stores (publish/out/poison): gives the
        // poison -> future-data-write happens-before chain via next publish
        asm volatile("s_waitcnt vmcnt(0)" ::: "memory");
        __syncthreads();   // B2
    }
}

// ---------------------------------------------------------------------------
extern "C" void kernel_launch(void* const* d_in, const int* in_sizes, int n_in,
                              void* d_out, int out_size, void* d_ws, size_t ws_size,
                              hipStream_t stream) {
    (void)in_sizes; (void)n_in; (void)out_size;

    const float* x      = (const float*)d_in[0];
    const float* attn_w = (const float*)d_in[1];
    const float* attn_b = (const float*)d_in[2];
    const float* W_ih   = (const float*)d_in[3];
    const float* W_hh   = (const float*)d_in[4];
    const float* b_ih   = (const float*)d_in[5];
    const float* b_hh   = (const float*)d_in[6];
    float* out = (float*)d_out;

    char* ws = (char*)d_ws;
    float* a_buf = (float*)ws;                 // 256 KiB
    float* bias  = (float*)(ws + 262144);      //   4 KiB
    f16*   Wfrag = (f16*)(ws + 266240);        // 768 KiB
    f16*   hx    = (f16*)(ws + 1052672);       //   2 MiB (8 slots)
    if (ws_size < (size_t)3149824) return;

    attn_kernel<<<NB, 128, 0, stream>>>(x, attn_w, attn_b, a_buf);
    pack_kernel<<<96, 512, 0, stream>>>(W_ih, W_hh, b_ih, b_hh, Wfrag, bias);
    poison_kernel<<<256, 512, 0, stream>>>((uint4*)hx);
    lstm_kernel<<<PGRP * QGRP, 512, 0, stream>>>(x, a_buf, bias, Wfrag, hx, out);
}

// Round 9
// 1989.819 us; speedup vs baseline: 1.2150x; 1.2150x over previous
//
#include <hip/hip_runtime.h>
#include <cstdint>

#define NB 512   // batch
#define ND 128   // D
#define NW 256   // timesteps
#define NH 256   // hidden
#define PGRP 32  // row groups (M=16 rows each)
#define QGRP 8   // col groups (32 h-cols each)
#define SLOTS 4
#define SENT32 0x7C007C00u
#define SENT64 0x7C007C007C007C00ull

typedef _Float16 f16;
typedef _Float16 h8 __attribute__((ext_vector_type(8)));
typedef float f32x4 __attribute__((ext_vector_type(4)));
typedef unsigned long long u64;

__device__ __forceinline__ float sigm(float v){ return 1.f/(1.f+__expf(-v)); }
__device__ __forceinline__ float tanh_fast(float v){
  v = fminf(fmaxf(v,-15.f),15.f);
  float e = __expf(2.f*v);
  return (e-1.f)/(e+1.f);
}

// ---------------------------------------------------------------------------
// a[b,d] = softmax_d( x[b,d,:] . w_x + attn_b )   (h/c term cancels in softmax)
// ---------------------------------------------------------------------------
__global__ __launch_bounds__(128) void attn_kernel(
    const float* __restrict__ x, const float* __restrict__ attn_w,
    const float* __restrict__ attn_b, float* __restrict__ a_buf)
{
    __shared__ float wx[NW];
    __shared__ float sred[2];
    const int b = blockIdx.x;
    const int d = threadIdx.x;

    wx[d]       = attn_w[2 * NH + d];
    wx[d + 128] = attn_w[2 * NH + d + 128];
    __syncthreads();

    const float4* xr = (const float4*)(x + ((size_t)b * ND + d) * NW);
    float acc = 0.f;
    #pragma unroll 8
    for (int w4 = 0; w4 < NW / 4; ++w4) {
        float4 v = xr[w4];
        acc += v.x * wx[w4*4+0] + v.y * wx[w4*4+1]
             + v.z * wx[w4*4+2] + v.w * wx[w4*4+3];
    }
    float e = acc + attn_b[0];

    float mx = e;
    #pragma unroll
    for (int o = 32; o > 0; o >>= 1) mx = fmaxf(mx, __shfl_xor(mx, o));
    if ((d & 63) == 0) sred[d >> 6] = mx;
    __syncthreads();
    mx = fmaxf(sred[0], sred[1]);
    __syncthreads();

    float p = __expf(e - mx);
    float s = p;
    #pragma unroll
    for (int o = 32; o > 0; o >>= 1) s += __shfl_xor(s, o);
    if ((d & 63) == 0) sred[d >> 6] = s;
    __syncthreads();
    s = sred[0] + sred[1];

    a_buf[(size_t)b * ND + d] = p / s;
}

// ---------------------------------------------------------------------------
// Pack W_aug = [W_hh | W_ih] into per-(q,wave,ktile) MFMA B-fragments (fp16).
// B-frag (16x16x32): lane l holds B[k = kt*32 + (l>>4)*8 + e][col16 = l&15],
// col16 -> (hcol_local = col16>>2, gate = col16&3).  (identical to round 3)
// ---------------------------------------------------------------------------
__global__ __launch_bounds__(512) void pack_kernel(
    const float* __restrict__ W_ih, const float* __restrict__ W_hh,
    const float* __restrict__ b_ih, const float* __restrict__ b_hh,
    f16* __restrict__ Wfrag, float* __restrict__ bias)
{
    int flat = blockIdx.x * 512 + threadIdx.x;   // 0..49151
    int l    = flat & 63;
    int kt   = (flat >> 6) % 12;
    int wq   = (flat >> 6) / 12;                 // q*8 + w
    int col16 = l & 15, kb = l >> 4;
    int hcol = (wq >> 3) * 32 + (wq & 7) * 4 + (col16 >> 2);
    int gate = col16 & 3;
    int n    = gate * 256 + hcol;
    int k0   = kt * 32 + kb * 8;

    f16 tmp[8];
    #pragma unroll
    for (int e = 0; e < 8; ++e) {
        int k = k0 + e;
        float v = (k < NH) ? W_hh[(size_t)n * NH + k]
                           : W_ih[(size_t)n * ND + (k - NH)];
        tmp[e] = (f16)v;
    }
    *(h8*)(Wfrag + (size_t)flat * 8) = *(const h8*)tmp;

    if (flat < 1024) bias[flat] = b_ih[flat] + b_hh[flat];
}

// poison all 4 hx slots with fp16-inf sentinel (|h|<1 always)
__global__ __launch_bounds__(512) void poison_kernel(uint4* __restrict__ hx4)
{
    uint4 v = {SENT32, SENT32, SENT32, SENT32};
    hx4[(size_t)blockIdx.x * 512 + threadIdx.x] = v;   // 128 blocks -> 1 MB
}

// ---------------------------------------------------------------------------
// Persistent LSTM: 256 blocks (bid = q*32 + p), 512 threads (8 waves).
// Block (p,q): rows p*16..+16, h-cols q*32..+32 (wave w: 4 hcols x 16 rows).
// Protocol (minimal-hop, self-flagging):
//  (a) ALL 512 threads speculatively load their own 16B of h(t-1) from slot
//      (t-1)&3 (relaxed agent atomics). In steady state the producer
//      published ~a step ago -> first probe returns real data.
//  (b) x-part MFMA (kt 8..11) overlaps the load latency. The compiler's
//      wait for these loads also drains ALL of step t-1's stores
//      (publish/out/poison) -> ordering chain with zero explicit vmcnt.
//  (c) detect per-thread (fp16-inf sentinel), land 16B into LDS buf[t&1].
//  B1  (d) poison: block q==(t&7) poisons its p-region of slot (t+2)&3
//      (= h(t-2): all readers provably finished, see B1 argument).
//      (e) h-part MFMA kt 0..7; scr-LDS gate transpose; LSTM cell.
//      (f) publish h(t) to slot t&3 (FIRST store, nothing drains before it);
//      out store; stage a*x(t+1) -> buf[(t+1)&1];  B2.
// Deadlock-free: producers publish step t with no dependency on step t data;
// consumers spin only on published data. Induction from t=0.
// ---------------------------------------------------------------------------
__global__ __launch_bounds__(512, 2) void lstm_kernel(
    const float* __restrict__ x, const float* __restrict__ a_buf,
    const float* __restrict__ bias, const f16* __restrict__ Wfrag,
    f16* __restrict__ hx, float* __restrict__ out)
{
    __shared__ __align__(16) unsigned char A16[2][16 * 768];  // 2 x 12 KB
    __shared__ float scr[8][272];                             // per-wave 16x16+pad

    const int tid = threadIdx.x;
    const int w = tid >> 6, l = tid & 63;
    const int p = blockIdx.x & 31, q = blockIdx.x >> 5;
    const int b0 = p * 16;

    // --- weights -> registers (persistent) ---
    h8 bfrag[12];
    {
        const h8* wsrc = (const h8*)Wfrag + ((q * 8 + w) * 12) * 64 + l;
        #pragma unroll
        for (int kt = 0; kt < 12; ++kt) bfrag[kt] = wsrc[kt * 64];
    }

    const int m = l >> 2, hh = l & 3;          // epilogue lane roles
    const int jcol = q * 32 + w * 4 + hh;
    float bias4[4];
    #pragma unroll
    for (int g = 0; g < 4; ++g) bias4[g] = bias[g * 256 + jcol];
    float cstate = 0.f;

    // --- roles ---
    const int xrow = tid >> 4, xdc = tid & 15; // x loader (tid<256)
    const int r2 = tid >> 5, kc = tid & 31;    // h role: 16 rows x 32 x 16B
    const int arow = l & 15, akb = l >> 4;     // A-frag read role

    float areg[8];
    const float* xbase = x;
    if (tid < 256) {
        int b = b0 + xrow;
        #pragma unroll
        for (int e = 0; e < 8; ++e) areg[e] = a_buf[b * ND + xdc * 8 + e];
        xbase = x + ((size_t)b * ND + xdc * 8) * NW;
    }
    float4 xq[8];

    // --- prologue: zero h-region of buf0; stage x_hat(0) ---
    {
        int byte = r2 * 768 + kc * 16;
        byte ^= (r2 & 7) << 4;
        h8 z = {};
        *(h8*)(A16[0] + byte) = z;
    }
    if (tid < 256) {
        #pragma unroll
        for (int e = 0; e < 8; ++e)
            xq[e] = *(const float4*)(xbase + (size_t)e * NW);
        f16 xv[8];
        #pragma unroll
        for (int e = 0; e < 8; ++e) {
            float xf = xq[e].x;
            xq[e] = make_float4(xq[e].y, xq[e].z, xq[e].w, xq[e].x);
            xv[e] = (f16)(xf * areg[e]);
        }
        int byte = xrow * 768 + 512 + xdc * 16;
        byte ^= (xrow & 7) << 4;
        *(h8*)(A16[0] + byte) = *(const h8*)xv;
    }
    __syncthreads();

    for (int t = 0; t < NW; ++t) {
        // --- (a) speculative h(t-1) loads, issued before any compute ---
        u64 d0 = 0, d1 = 0;
        const u64* src = nullptr;
        if (t > 0) {
            src = (const u64*)hx
                + (((size_t)((t - 1) & 3)) * NB + b0 + r2) * 64 + kc * 2;
            d0 = __hip_atomic_load(src + 0, __ATOMIC_RELAXED, __HIP_MEMORY_SCOPE_AGENT);
            d1 = __hip_atomic_load(src + 1, __ATOMIC_RELAXED, __HIP_MEMORY_SCOPE_AGENT);
        }

        // --- (b) x-part MFMA (kt 8..11), load latency hidden ---
        f32x4 acc = {0.f, 0.f, 0.f, 0.f};
        #pragma unroll
        for (int kt = 8; kt < 12; ++kt) {
            int byte = arow * 768 + kt * 64 + akb * 16;
            byte ^= (arow & 7) << 4;
            h8 afrag = *(const h8*)(A16[t & 1] + byte);
            acc = __builtin_amdgcn_mfma_f32_16x16x32_f16(afrag, bfrag[kt], acc, 0, 0, 0);
        }

        // --- (c) detect (self-flagging) + land 16B into LDS ---
        if (t > 0) {
            for (;;) {
                if ((unsigned)d0 != SENT32 && (unsigned)(d0 >> 32) != SENT32 &&
                    (unsigned)d1 != SENT32 && (unsigned)(d1 >> 32) != SENT32) break;
                __builtin_amdgcn_s_sleep(1);
                d0 = __hip_atomic_load(src + 0, __ATOMIC_RELAXED, __HIP_MEMORY_SCOPE_AGENT);
                d1 = __hip_atomic_load(src + 1, __ATOMIC_RELAXED, __HIP_MEMORY_SCOPE_AGENT);
            }
            int byte = r2 * 768 + kc * 16;
            byte ^= (r2 & 7) << 4;
            ((u64*)(A16[t & 1] + byte))[0] = d0;
            ((u64*)(A16[t & 1] + byte))[1] = d1;
        }
        __syncthreads();   // B1: full h(t-1) in LDS; all producers past B1(t-1)

        // --- (d) rotating poisoner: slot (t+2)&3 (= h(t-2), readers done) ---
        if (q == (t & 7)) {
            u64* pz = (u64*)hx
                + (((size_t)((t + 2) & 3)) * NB + b0 + r2) * 64 + kc * 2;
            __hip_atomic_store(pz + 0, SENT64, __ATOMIC_RELAXED, __HIP_MEMORY_SCOPE_AGENT);
            __hip_atomic_store(pz + 1, SENT64, __ATOMIC_RELAXED, __HIP_MEMORY_SCOPE_AGENT);
        }

        // --- (e) h-part MFMA (kt 0..7) ---
        #pragma unroll
        for (int kt = 0; kt < 8; ++kt) {
            int byte = arow * 768 + kt * 64 + akb * 16;
            byte ^= (arow & 7) << 4;
            h8 afrag = *(const h8*)(A16[t & 1] + byte);
            acc = __builtin_amdgcn_mfma_f32_16x16x32_f16(afrag, bfrag[kt], acc, 0, 0, 0);
        }

        // --- epilogue: gate transpose via per-wave LDS, LSTM cell ---
        float hn;
        {
            float* sw = &scr[w][0];
            int col = l & 15, rb = (l >> 4) * 4;
            sw[(rb + 0) * 17 + col] = acc[0];
            sw[(rb + 1) * 17 + col] = acc[1];
            sw[(rb + 2) * 17 + col] = acc[2];
            sw[(rb + 3) * 17 + col] = acc[3];
            asm volatile("s_waitcnt lgkmcnt(0)" ::: "memory");
            float G0 = sw[m * 17 + hh * 4 + 0] + bias4[0];
            float G1 = sw[m * 17 + hh * 4 + 1] + bias4[1];
            float G2 = sw[m * 17 + hh * 4 + 2] + bias4[2];
            float G3 = sw[m * 17 + hh * 4 + 3] + bias4[3];
            float ig = sigm(G0), fg = sigm(G1);
            float gg = tanh_fast(G2), og = sigm(G3);
            cstate = fg * cstate + ig * gg;
            hn = og * tanh_fast(cstate);

            // (f) publish h(t) FIRST — the only thing consumers wait on
            f16 hf = (f16)hn;
            unsigned short hb = __builtin_bit_cast(unsigned short, hf);
            int other = __shfl_xor((int)hb, 1);
            if (!(l & 1)) {
                unsigned val = (unsigned)hb | ((unsigned)(unsigned short)other << 16);
                unsigned* dst = (unsigned*)((unsigned short*)hx
                                + ((size_t)(t & 3) * NB + b0 + m) * NH + jcol);
                __hip_atomic_store(dst, val, __ATOMIC_RELAXED, __HIP_MEMORY_SCOPE_AGENT);
            }
        }

        // out store (drained implicitly by next step's spec-load wait)
        out[((size_t)(b0 + m) * NW + t) * NH + jcol] = hn;

        // stage x_hat(t+1) into buf[(t+1)&1]
        if (tid < 256 && t + 1 < NW) {
            if (((t + 1) & 3) == 0) {
                #pragma unroll
                for (int e = 0; e < 8; ++e)
                    xq[e] = *(const float4*)(xbase + (size_t)e * NW + (t + 1));
            }
            f16 xv[8];
            #pragma unroll
            for (int e = 0; e < 8; ++e) {
                float xf = xq[e].x;
                xq[e] = make_float4(xq[e].y, xq[e].z, xq[e].w, xq[e].x);
                xv[e] = (f16)(xf * areg[e]);
            }
            int byte = xrow * 768 + 512 + xdc * 16;
            byte ^= (xrow & 7) << 4;
            *(h8*)(A16[(t + 1) & 1] + byte) = *(const h8*)xv;
        }
        __syncthreads();   // B2
    }
}

// ---------------------------------------------------------------------------
extern "C" void kernel_launch(void* const* d_in, const int* in_sizes, int n_in,
                              void* d_out, int out_size, void* d_ws, size_t ws_size,
                              hipStream_t stream) {
    (void)in_sizes; (void)n_in; (void)out_size;

    const float* x      = (const float*)d_in[0];
    const float* attn_w = (const float*)d_in[1];
    const float* attn_b = (const float*)d_in[2];
    const float* W_ih   = (const float*)d_in[3];
    const float* W_hh   = (const float*)d_in[4];
    const float* b_ih   = (const float*)d_in[5];
    const float* b_hh   = (const float*)d_in[6];
    float* out = (float*)d_out;

    char* ws = (char*)d_ws;
    float* a_buf = (float*)ws;                 // 256 KiB
    float* bias  = (float*)(ws + 262144);      //   4 KiB
    f16*   Wfrag = (f16*)(ws + 266240);        // 768 KiB
    f16*   hx    = (f16*)(ws + 1052672);       //   1 MiB (4 slots)
    if (ws_size < (size_t)2101248) return;

    attn_kernel<<<NB, 128, 0, stream>>>(x, attn_w, attn_b, a_buf);
    pack_kernel<<<96, 512, 0, stream>>>(W_ih, W_hh, b_ih, b_hh, Wfrag, bias);
    poison_kernel<<<128, 512, 0, stream>>>((uint4*)hx);
    lstm_kernel<<<PGRP * QGRP, 512, 0, stream>>>(x, a_buf, bias, Wfrag, hx, out);
}

// Round 10
// 761.372 us; speedup vs baseline: 3.1753x; 2.6135x over previous
//
#include <hip/hip_runtime.h>
#include <cstdint>

#define NB 512   // batch
#define ND 128   // D
#define NW 256   // timesteps
#define NH 256   // hidden
#define PGRP 32  // row groups (M=16 rows each)
#define QGRP 8   // col groups (32 h-cols each)

typedef _Float16 f16;
typedef _Float16 h8 __attribute__((ext_vector_type(8)));
typedef float f32x4 __attribute__((ext_vector_type(4)));
typedef unsigned long long u64;

#define FLAG_DONE 0x0101010101010101ull

__device__ __forceinline__ float sigm(float v){ return 1.f/(1.f+__expf(-v)); }
__device__ __forceinline__ float tanh_fast(float v){
  v = fminf(fmaxf(v,-15.f),15.f);
  float e = __expf(2.f*v);
  return (e-1.f)/(e+1.f);
}

// ---------------------------------------------------------------------------
// a[b,d] = softmax_d( x[b,d,:] . w_x + attn_b )   (h/c term cancels in softmax)
// ---------------------------------------------------------------------------
__global__ __launch_bounds__(128) void attn_kernel(
    const float* __restrict__ x, const float* __restrict__ attn_w,
    const float* __restrict__ attn_b, float* __restrict__ a_buf)
{
    __shared__ float wx[NW];
    __shared__ float sred[2];
    const int b = blockIdx.x;
    const int d = threadIdx.x;

    wx[d]       = attn_w[2 * NH + d];
    wx[d + 128] = attn_w[2 * NH + d + 128];
    __syncthreads();

    const float4* xr = (const float4*)(x + ((size_t)b * ND + d) * NW);
    float acc = 0.f;
    #pragma unroll 8
    for (int w4 = 0; w4 < NW / 4; ++w4) {
        float4 v = xr[w4];
        acc += v.x * wx[w4*4+0] + v.y * wx[w4*4+1]
             + v.z * wx[w4*4+2] + v.w * wx[w4*4+3];
    }
    float e = acc + attn_b[0];

    float mx = e;
    #pragma unroll
    for (int o = 32; o > 0; o >>= 1) mx = fmaxf(mx, __shfl_xor(mx, o));
    if ((d & 63) == 0) sred[d >> 6] = mx;
    __syncthreads();
    mx = fmaxf(sred[0], sred[1]);
    __syncthreads();

    float p = __expf(e - mx);
    float s = p;
    #pragma unroll
    for (int o = 32; o > 0; o >>= 1) s += __shfl_xor(s, o);
    if ((d & 63) == 0) sred[d >> 6] = s;
    __syncthreads();
    s = sred[0] + sred[1];

    a_buf[(size_t)b * ND + d] = p / s;
}

// ---------------------------------------------------------------------------
// Pack W_aug = [W_hh | W_ih] into per-(q,wave,ktile) MFMA B-fragments (fp16).
// B-frag (16x16x32): lane l holds B[k = kt*32 + (l>>4)*8 + e][col16 = l&15],
// col16 -> (hcol_local = col16>>2, gate = col16&3).
// ---------------------------------------------------------------------------
__global__ __launch_bounds__(512) void pack_kernel(
    const float* __restrict__ W_ih, const float* __restrict__ W_hh,
    const float* __restrict__ b_ih, const float* __restrict__ b_hh,
    f16* __restrict__ Wfrag, float* __restrict__ bias)
{
    int flat = blockIdx.x * 512 + threadIdx.x;   // 0..49151
    int l    = flat & 63;
    int kt   = (flat >> 6) % 12;
    int wq   = (flat >> 6) / 12;                 // q*8 + w
    int col16 = l & 15, kb = l >> 4;
    int hcol = (wq >> 3) * 32 + (wq & 7) * 4 + (col16 >> 2);
    int gate = col16 & 3;
    int n    = gate * 256 + hcol;
    int k0   = kt * 32 + kb * 8;

    f16 tmp[8];
    #pragma unroll
    for (int e = 0; e < 8; ++e) {
        int k = k0 + e;
        float v = (k < NH) ? W_hh[(size_t)n * NH + k]
                           : W_ih[(size_t)n * ND + (k - NH)];
        tmp[e] = (f16)v;
    }
    *(h8*)(Wfrag + (size_t)flat * 8) = *(const h8*)tmp;

    if (flat < 1024) bias[flat] = b_ih[flat] + b_hh[flat];
}

__global__ __launch_bounds__(512) void init_kernel(unsigned* __restrict__ flags)
{
    flags[blockIdx.x * 512 + threadIdx.x] = 0u;   // grid 32 -> 16384 u32 = 64KB
}

// ---------------------------------------------------------------------------
// Persistent LSTM (round-3 proven structure): 256 blocks (bid = q*32 + p),
// 512 threads (8 waves). Block (p,q): rows p*16..+16, h-cols q*32..+32.
// W slice resident in VGPRs (bfrag[12]).
// Per step: A=[h | a*x_t] (16x384 f16) in LDS; x-part MFMA overlaps hx loads;
// h exchange via hx (fp16, agent-scope) + byte-packed u64 flag per (t,p):
// writer block q stores byte q after per-wave vmcnt(0)+barrier; reader tid0
// polls one u64 == 0x0101..01, then __syncthreads releases the block.
// NEW vs r3: tid0 issues a SPECULATIVE flag probe at end of step t; if it
// already reads FLAG_DONE the poll at t+1 is skipped (saves one L3 RT).
// ---------------------------------------------------------------------------
__global__ __launch_bounds__(512, 2) void lstm_kernel(
    const float* __restrict__ x, const float* __restrict__ a_buf,
    const float* __restrict__ bias, const f16* __restrict__ Wfrag,
    f16* __restrict__ hx, u64* __restrict__ flags,
    float* __restrict__ out)
{
    __shared__ __align__(16) unsigned char A16[16 * 768];  // 16 rows x 384 f16
    __shared__ float scr[8][272];                           // per-wave 16x16 +pad

    const int tid = threadIdx.x;
    const int w = tid >> 6, l = tid & 63;
    const int p = blockIdx.x & 31, q = blockIdx.x >> 5;

    // --- weights -> registers (persistent) ---
    h8 bfrag[12];
    {
        const h8* wsrc = (const h8*)Wfrag + ((q * 8 + w) * 12) * 64 + l;
        #pragma unroll
        for (int kt = 0; kt < 12; ++kt) bfrag[kt] = wsrc[kt * 64];
    }

    const int m = l >> 2, hh = l & 3;          // epilogue lane roles
    const int jcol = q * 32 + w * 4 + hh;
    float bias4[4];
    #pragma unroll
    for (int g = 0; g < 4; ++g) bias4[g] = bias[g * 256 + jcol];
    float cstate = 0.f;

    // --- x loader roles (threads 0..255): 16 rows x 16 d-chunks ---
    float areg[8];
    const float* xbase = nullptr;
    const int xrow = tid >> 4, xdc = tid & 15;
    if (tid < 256) {
        int b = p * 16 + xrow;
        #pragma unroll
        for (int e = 0; e < 8; ++e) areg[e] = a_buf[b * ND + xdc * 8 + e];
        xbase = x + ((size_t)b * ND + xdc * 8) * NW;
    }
    const int r2 = tid >> 5, kc = tid & 31;    // h role: 16 rows x 32 chunks
    const int arow = l & 15, akb = l >> 4;     // A-frag role

    float4 xq[8];
    u64 fl_spec = 0;                           // speculative flag value

    // --- prologue: zero h-region of A16; stage x(t=0) ---
    {
        int byte = r2 * 768 + kc * 16;
        byte ^= (r2 & 7) << 4;
        h8 z = {};
        *(h8*)(A16 + byte) = z;
    }
    if (tid < 256) {
        #pragma unroll
        for (int e = 0; e < 8; ++e)
            xq[e] = *(const float4*)(xbase + (size_t)e * NW);
        f16 xv[8];
        #pragma unroll
        for (int e = 0; e < 8; ++e) {
            float xf = xq[e].x;
            xq[e] = make_float4(xq[e].y, xq[e].z, xq[e].w, xq[e].x);
            xv[e] = (f16)(xf * areg[e]);
        }
        int byte = xrow * 768 + 512 + xdc * 16;
        byte ^= (xrow & 7) << 4;
        *(h8*)(A16 + byte) = *(const h8*)xv;
    }

    for (int t = 0; t < NW; ++t) {
        // --- B1: wait for h_{t-1} published by all 8 sibling blocks ---
        if (t > 0 && tid == 0 && fl_spec != FLAG_DONE) {
            while (__hip_atomic_load(&flags[(t - 1) * PGRP + p],
                                     __ATOMIC_RELAXED, __HIP_MEMORY_SCOPE_AGENT)
                   != FLAG_DONE) {}
        }
        __syncthreads();

        f32x4 acc = {0.f, 0.f, 0.f, 0.f};
        if (t > 0) {
            // issue hx loads first (L3 latency hidden under x-part MFMA)
            const u64* hrow = (const u64*)
                (hx + ((size_t)((t - 1) & 1) * NB + p * 16 + r2) * NH);
            u64 d0 = __hip_atomic_load(hrow + kc * 2 + 0,
                    __ATOMIC_RELAXED, __HIP_MEMORY_SCOPE_AGENT);
            u64 d1 = __hip_atomic_load(hrow + kc * 2 + 1,
                    __ATOMIC_RELAXED, __HIP_MEMORY_SCOPE_AGENT);
            #pragma unroll
            for (int kt = 8; kt < 12; ++kt) {      // x-part (no h dependency)
                int byte = arow * 768 + kt * 64 + akb * 16;
                byte ^= (arow & 7) << 4;
                h8 afrag = *(const h8*)(A16 + byte);
                acc = __builtin_amdgcn_mfma_f32_16x16x32_f16(afrag, bfrag[kt], acc, 0, 0, 0);
            }
            int byte = r2 * 768 + kc * 16;
            byte ^= (r2 & 7) << 4;
            ((u64*)(A16 + byte))[0] = d0;
            ((u64*)(A16 + byte))[1] = d1;
        } else {
            #pragma unroll
            for (int kt = 8; kt < 12; ++kt) {
                int byte = arow * 768 + kt * 64 + akb * 16;
                byte ^= (arow & 7) << 4;
                h8 afrag = *(const h8*)(A16 + byte);
                acc = __builtin_amdgcn_mfma_f32_16x16x32_f16(afrag, bfrag[kt], acc, 0, 0, 0);
            }
        }
        __syncthreads();   // B2: A16 h-region ready

        #pragma unroll
        for (int kt = 0; kt < 8; ++kt) {           // h-part
            int byte = arow * 768 + kt * 64 + akb * 16;
            byte ^= (arow & 7) << 4;
            h8 afrag = *(const h8*)(A16 + byte);
            acc = __builtin_amdgcn_mfma_f32_16x16x32_f16(afrag, bfrag[kt], acc, 0, 0, 0);
        }

        // --- epilogue: gate transpose via per-wave LDS, LSTM cell ---
        float hn;
        {
            float* sw = &scr[w][0];
            int col = l & 15, rb = (l >> 4) * 4;
            sw[(rb + 0) * 17 + col] = acc[0];
            sw[(rb + 1) * 17 + col] = acc[1];
            sw[(rb + 2) * 17 + col] = acc[2];
            sw[(rb + 3) * 17 + col] = acc[3];
            asm volatile("s_waitcnt lgkmcnt(0)" ::: "memory");
            float G0 = sw[m * 17 + hh * 4 + 0] + bias4[0];
            float G1 = sw[m * 17 + hh * 4 + 1] + bias4[1];
            float G2 = sw[m * 17 + hh * 4 + 2] + bias4[2];
            float G3 = sw[m * 17 + hh * 4 + 3] + bias4[3];
            float ig = sigm(G0), fg = sigm(G1);
            float gg = tanh_fast(G2), og = sigm(G3);
            cstate = fg * cstate + ig * gg;
            hn = og * tanh_fast(cstate);

            // publish h (fp16, agent scope) FIRST — starts the L3 round trip
            f16 hf = (f16)hn;
            unsigned short hb = __builtin_bit_cast(unsigned short, hf);
            int other = __shfl_xor((int)hb, 1);
            if (!(l & 1)) {
                unsigned val = (unsigned)hb | ((unsigned)(unsigned short)other << 16);
                unsigned* dst = (unsigned*)((unsigned short*)hx
                                + ((size_t)(t & 1) * NB + p * 16 + m) * NH + jcol);
                __hip_atomic_store(dst, val, __ATOMIC_RELAXED, __HIP_MEMORY_SCOPE_AGENT);
            }
        }
        asm volatile("s_waitcnt vmcnt(0)" ::: "memory");  // per-wave publish ack
        __syncthreads();   // B3: all waves' publishes ack'd

        if (tid == 0 && t < NW - 1) {
            unsigned char* fb = ((unsigned char*)&flags[t * PGRP + p]) + q;
            __hip_atomic_store(fb, (unsigned char)1,
                               __ATOMIC_RELAXED, __HIP_MEMORY_SCOPE_AGENT);
        }

        // out store (plain — adjacent waves' 16B chunks merge to full lines)
        out[((size_t)(p * 16 + m) * NW + t) * NH + jcol] = hn;

        // stage x(t+1) (off critical path; next B1 orders it for readers)
        if (tid < 256 && t + 1 < NW) {
            if (((t + 1) & 3) == 0) {
                #pragma unroll
                for (int e = 0; e < 8; ++e)
                    xq[e] = *(const float4*)(xbase + (size_t)e * NW + (t + 1));
            }
            f16 xv[8];
            #pragma unroll
            for (int e = 0; e < 8; ++e) {
                float xf = xq[e].x;
                xq[e] = make_float4(xq[e].y, xq[e].z, xq[e].w, xq[e].x);
                xv[e] = (f16)(xf * areg[e]);
            }
            int byte = xrow * 768 + 512 + xdc * 16;
            byte ^= (xrow & 7) << 4;
            *(h8*)(A16 + byte) = *(const h8*)xv;
        }

        // speculative probe of THIS step's flag (checked at next B1);
        // issued ~0.5us after publish -> hits iff flag visibility < ~0.6us
        if (tid == 0 && t < NW - 1) {
            fl_spec = __hip_atomic_load(&flags[t * PGRP + p],
                                        __ATOMIC_RELAXED, __HIP_MEMORY_SCOPE_AGENT);
        }
    }
}

// ---------------------------------------------------------------------------
extern "C" void kernel_launch(void* const* d_in, const int* in_sizes, int n_in,
                              void* d_out, int out_size, void* d_ws, size_t ws_size,
                              hipStream_t stream) {
    (void)in_sizes; (void)n_in; (void)out_size;

    const float* x      = (const float*)d_in[0];
    const float* attn_w = (const float*)d_in[1];
    const float* attn_b = (const float*)d_in[2];
    const float* W_ih   = (const float*)d_in[3];
    const float* W_hh   = (const float*)d_in[4];
    const float* b_ih   = (const float*)d_in[5];
    const float* b_hh   = (const float*)d_in[6];
    float* out = (float*)d_out;

    char* ws = (char*)d_ws;
    float* a_buf = (float*)ws;                 // 256 KiB
    float* bias  = (float*)(ws + 262144);      //   4 KiB
    f16*   Wfrag = (f16*)(ws + 266240);        // 768 KiB
    f16*   hx    = (f16*)(ws + 1052672);       // 512 KiB (2 slots)
    u64*   flags = (u64*)(ws + 1576960);       //  64 KiB (NW*PGRP u64)
    if (ws_size < (size_t)1642496) return;

    attn_kernel<<<NB, 128, 0, stream>>>(x, attn_w, attn_b, a_buf);
    pack_kernel<<<96, 512, 0, stream>>>(W_ih, W_hh, b_ih, b_hh, Wfrag, bias);
    init_kernel<<<32, 512, 0, stream>>>((unsigned*)flags);
    lstm_kernel<<<PGRP * QGRP, 512, 0, stream>>>(x, a_buf, bias, Wfrag, hx, flags, out);
}